// Round 2
// baseline (90740.680 us; speedup 1.0000x reference)
//
#include <hip/hip_runtime.h>
#include <hip/hip_cooperative_groups.h>
#include <math.h>

#define T_STEPS 512
#define BATCH   64
#define IDIM    512
#define DDIM    1024
#define KTOT    (DDIM + IDIM)   // 1536

namespace cg = cooperative_groups;

// ---------------------------------------------------------------------------
// One-time: transpose state_below [T][B][I] -> paired sbTp [T][I/2][B][2]
//   sbTp[((t*256 + ip)*64 + b)*2 + par] = sb[t][b][2*ip+par]
// ---------------------------------------------------------------------------
__global__ __launch_bounds__(256) void k_transpose_sb(const float* __restrict__ sb,
                                                      float* __restrict__ sbTp) {
    __shared__ float tile[64][65];
    int bid = blockIdx.x;
    int t  = bid >> 3;          // 8 chunks of 64 i's per t
    int i0 = (bid & 7) << 6;
    const float* src = sb + (size_t)t * BATCH * IDIM;
    int tid = threadIdx.x;
    int row = tid >> 4;         // 0..15
    int c4  = (tid & 15) << 2;  // 0..60
#pragma unroll
    for (int rep = 0; rep < 4; ++rep) {
        int b = row + rep * 16;
        float4 v = *reinterpret_cast<const float4*>(src + (size_t)b * IDIM + i0 + c4);
        tile[b][c4 + 0] = v.x; tile[b][c4 + 1] = v.y;
        tile[b][c4 + 2] = v.z; tile[b][c4 + 3] = v.w;
    }
    __syncthreads();
    int bp   = tid & 31;        // b-pair index
    int b0   = bp << 1;
    int ipl0 = tid >> 5;        // 0..7
    float* dst = sbTp + ((size_t)t * 256 + (i0 >> 1)) * 128;
#pragma unroll
    for (int r = 0; r < 4; ++r) {
        int ipl = ipl0 + (r << 3);   // 0..31 local i-pair
        int il  = ipl << 1;
        float4 v;
        v.x = tile[b0][il];     v.y = tile[b0][il + 1];
        v.z = tile[b0 + 1][il]; v.w = tile[b0 + 1][il + 1];
        *reinterpret_cast<float4*>(dst + (size_t)ipl * 128 + (b0 << 1)) = v;
    }
}

// ---------------------------------------------------------------------------
// One-time: build Wt[3][DDIM][KTOT]  (g=0: r-gate col, g=1: u-gate col,
// g=2: candidate col; rows k<1024 from U/Ux, k>=1024 from W/Wx)
// ---------------------------------------------------------------------------
__global__ __launch_bounds__(256) void k_build_wt(const float* __restrict__ U,
                                                  const float* __restrict__ Ux,
                                                  const float* __restrict__ W,
                                                  const float* __restrict__ Wx,
                                                  float* __restrict__ Wt) {
    __shared__ float tile[64][65];
    int bid = blockIdx.x;
    int g  = bid / (16 * 24);
    int r  = bid % (16 * 24);
    int dt = r / 24;
    int kt = r % 24;
    int d0 = dt << 6;
    int k0 = kt << 6;
    int tid = threadIdx.x;
    int row = tid >> 4;
    int c4  = (tid & 15) << 2;
#pragma unroll
    for (int rep = 0; rep < 4; ++rep) {
        int kk = row + rep * 16;
        int k = k0 + kk;
        const float* srcrow;
        if (k < DDIM) {
            srcrow = (g == 2) ? (Ux + (size_t)k * DDIM)
                              : (U + (size_t)k * (2 * DDIM) + (g == 1 ? DDIM : 0));
        } else {
            int kp = k - DDIM;
            srcrow = (g == 2) ? (Wx + (size_t)kp * DDIM)
                              : (W + (size_t)kp * (2 * DDIM) + (g == 1 ? DDIM : 0));
        }
        float4 v = *reinterpret_cast<const float4*>(srcrow + d0 + c4);
        tile[kk][c4 + 0] = v.x; tile[kk][c4 + 1] = v.y;
        tile[kk][c4 + 2] = v.z; tile[kk][c4 + 3] = v.w;
    }
    __syncthreads();
    float* dst = Wt + ((size_t)g * DDIM + d0) * KTOT + k0;
#pragma unroll
    for (int rep = 0; rep < 4; ++rep) {
        int dd = row + rep * 16;
        float4 v;
        v.x = tile[c4 + 0][dd]; v.y = tile[c4 + 1][dd];
        v.z = tile[c4 + 2][dd]; v.w = tile[c4 + 3][dd];
        *reinterpret_cast<float4*>(dst + (size_t)dd * KTOT + c4) = v;
    }
}

// ---------------------------------------------------------------------------
// Persistent cooperative scan kernel.
// 512 blocks x 256 threads (4 waves). Block owns d0=2*bid, d1=2*bid+1.
// wave wid: dl = wid>>1 (which d), kw = wid&1 (K half: [0,768) or [768,1536)).
// lane = batch b. Weights in LDS (staged once). h ping-pong in global,
// paired layout hT[(dpair*64+b)*2+par]. One grid.sync per timestep.
// ---------------------------------------------------------------------------
__global__ __launch_bounds__(256, 2) void k_scan(const float* __restrict__ Wt,
                                                 const float* __restrict__ sbTp,
                                                 const float* __restrict__ mask,
                                                 const float* __restrict__ bW,
                                                 const float* __restrict__ bWx,
                                                 float* __restrict__ hT,
                                                 float* __restrict__ out) {
    __shared__ float ldsW[2 * 3 * KTOT];   // 36,864 B
    __shared__ float red[4][4][64];        //  4,096 B

    int tid  = threadIdx.x;
    int lane = tid & 63;
    int wid  = tid >> 6;
    int dl   = wid >> 1;
    int kw   = wid & 1;
    int bid  = blockIdx.x;
    int d    = (bid << 1) + dl;

    // ---- stage this block's 2x3 weight columns into LDS (float4, coalesced)
    for (int j = tid; j < 2 * 3 * (KTOT / 4); j += 256) {
        int dl2 = j / (3 * (KTOT / 4));
        int rem = j - dl2 * (3 * (KTOT / 4));
        int g   = rem / (KTOT / 4);
        int k4  = rem - g * (KTOT / 4);
        float4 v = *reinterpret_cast<const float4*>(
            Wt + ((size_t)g * DDIM + (bid << 1) + dl2) * KTOT + (k4 << 2));
        *reinterpret_cast<float4*>(&ldsW[(dl2 * 3 + g) * KTOT + (k4 << 2)]) = v;
    }

    float bWr = bW[d];
    float bWu = bW[DDIM + d];
    float bXx = bWx[d];
    float hreg = 0.f;   // this wave's h[d][lane] (valid in kw==0 waves)
    __syncthreads();

    const float* wR = &ldsW[(dl * 3 + 0) * KTOT];
    const float* wU = &ldsW[(dl * 3 + 1) * KTOT];
    const float* wX = &ldsW[(dl * 3 + 2) * KTOT];

    cg::grid_group grid = cg::this_grid();

    for (int t = 0; t < T_STEPS; ++t) {
        const float* hp = hT + (size_t)(t & 1) * (DDIM * BATCH);
        float*       hn = hT + (size_t)((t + 1) & 1) * (DDIM * BATCH);
        const float* xp = sbTp + (size_t)t * (IDIM * BATCH);

        float aR0 = 0.f, aR1 = 0.f, aU0 = 0.f, aU1 = 0.f;
        float aH0 = 0.f, aH1 = 0.f, aX0 = 0.f, aX1 = 0.f;

        if (kw == 0) {
            // k in [0, 768): all recurrent (h)
            if (t > 0) {
#pragma unroll 8
                for (int kp = 0; kp < 384; kp += 2) {
                    float2 h0 = *reinterpret_cast<const float2*>(hp + ((kp * 64 + lane) << 1));
                    float2 h1 = *reinterpret_cast<const float2*>(hp + (((kp + 1) * 64 + lane) << 1));
                    float4 wr = *reinterpret_cast<const float4*>(wR + (kp << 1));
                    float4 wu = *reinterpret_cast<const float4*>(wU + (kp << 1));
                    float4 wx = *reinterpret_cast<const float4*>(wX + (kp << 1));
                    aR0 += h0.x * wr.x + h0.y * wr.y;  aR1 += h1.x * wr.z + h1.y * wr.w;
                    aU0 += h0.x * wu.x + h0.y * wu.y;  aU1 += h1.x * wu.z + h1.y * wu.w;
                    aH0 += h0.x * wx.x + h0.y * wx.y;  aH1 += h1.x * wx.z + h1.y * wx.w;
                }
            }
        } else {
            // k in [768, 1024): recurrent tail
            if (t > 0) {
#pragma unroll 8
                for (int kp = 384; kp < 512; kp += 2) {
                    float2 h0 = *reinterpret_cast<const float2*>(hp + ((kp * 64 + lane) << 1));
                    float2 h1 = *reinterpret_cast<const float2*>(hp + (((kp + 1) * 64 + lane) << 1));
                    float4 wr = *reinterpret_cast<const float4*>(wR + (kp << 1));
                    float4 wu = *reinterpret_cast<const float4*>(wU + (kp << 1));
                    float4 wx = *reinterpret_cast<const float4*>(wX + (kp << 1));
                    aR0 += h0.x * wr.x + h0.y * wr.y;  aR1 += h1.x * wr.z + h1.y * wr.w;
                    aU0 += h0.x * wu.x + h0.y * wu.y;  aU1 += h1.x * wu.z + h1.y * wu.w;
                    aH0 += h0.x * wx.x + h0.y * wx.y;  aH1 += h1.x * wx.z + h1.y * wx.w;
                }
            }
            // k in [1024, 1536): input part (x) — R/U sum with h-part; Xx separate
#pragma unroll 8
            for (int kp = 512; kp < 768; kp += 2) {
                float2 x0 = *reinterpret_cast<const float2*>(xp + (((kp - 512) * 64 + lane) << 1));
                float2 x1 = *reinterpret_cast<const float2*>(xp + (((kp - 511) * 64 + lane) << 1));
                float4 wr = *reinterpret_cast<const float4*>(wR + (kp << 1));
                float4 wu = *reinterpret_cast<const float4*>(wU + (kp << 1));
                float4 wx = *reinterpret_cast<const float4*>(wX + (kp << 1));
                aR0 += x0.x * wr.x + x0.y * wr.y;  aR1 += x1.x * wr.z + x1.y * wr.w;
                aU0 += x0.x * wu.x + x0.y * wu.y;  aU1 += x1.x * wu.z + x1.y * wu.w;
                aX0 += x0.x * wx.x + x0.y * wx.y;  aX1 += x1.x * wx.z + x1.y * wx.w;
            }
        }

        red[wid][0][lane] = aR0 + aR1;
        red[wid][1][lane] = aU0 + aU1;
        red[wid][2][lane] = aH0 + aH1;
        red[wid][3][lane] = aX0 + aX1;
        __syncthreads();

        if (kw == 0) {
            float R  = red[wid][0][lane] + red[wid + 1][0][lane] + bWr;
            float Uv = red[wid][1][lane] + red[wid + 1][1][lane] + bWu;
            float Hu = red[wid][2][lane] + red[wid + 1][2][lane];
            float Xx = red[wid][3][lane] + red[wid + 1][3][lane] + bXx;
            float m  = mask[(t << 6) + lane];

            float r  = 1.f / (1.f + expf(-R));
            float uu = 1.f / (1.f + expf(-Uv));
            float hc = tanhf(Hu * r + Xx);
            float hnew = uu * hreg + (1.f - uu) * hc;
            hnew = m * hnew + (1.f - m) * hreg;
            hreg = hnew;

            hn[((bid << 6) + lane) * 2 + dl] = hnew;                 // paired h
            out[(size_t)t * (BATCH * DDIM) + (lane << 10) + d] = hnew;
        }

        __threadfence();
        grid.sync();
    }
}

// ---------------------------------------------------------------------------
extern "C" void kernel_launch(void* const* d_in, const int* in_sizes, int n_in,
                              void* d_out, int out_size, void* d_ws, size_t ws_size,
                              hipStream_t stream) {
    const float* sb   = (const float*)d_in[0];
    const float* mask = (const float*)d_in[1];
    const float* W    = (const float*)d_in[2];
    const float* bW   = (const float*)d_in[3];
    const float* Wx   = (const float*)d_in[4];
    const float* bWx  = (const float*)d_in[5];
    const float* U    = (const float*)d_in[6];
    const float* Ux   = (const float*)d_in[7];
    float* out = (float*)d_out;
    float* ws  = (float*)d_ws;

    float* Wt   = ws;                                    // 3*1024*1536 f = 18.9 MB
    float* sbTp = Wt + (size_t)3 * DDIM * KTOT;          // 512*512*64 f  = 67.1 MB
    float* hT   = sbTp + (size_t)T_STEPS * IDIM * BATCH; // 2*1024*64 f   = 0.5 MB

    k_build_wt<<<dim3(3 * 16 * 24), 256, 0, stream>>>(U, Ux, W, Wx, Wt);
    k_transpose_sb<<<dim3(T_STEPS * (IDIM / 64)), 256, 0, stream>>>(sb, sbTp);

    void* args[] = {(void*)&Wt, (void*)&sbTp, (void*)&mask,
                    (void*)&bW, (void*)&bWx, (void*)&hT, (void*)&out};
    hipLaunchCooperativeKernel((const void*)k_scan, dim3(512), dim3(256),
                               args, 0, stream);
}

// Round 3
// 20049.240 us; speedup vs baseline: 4.5259x; 4.5259x over previous
//
#include <hip/hip_runtime.h>
#include <math.h>

#define T_STEPS 512
#define BATCH   64
#define IDIM    512
#define DDIM    1024
#define KTOT    1536
#define NCOLS   3072          // [dt 0..255][dl 0..3][g 0..2]
#define KSL     16            // k-slices = waves per block
#define KPS     96            // k per slice

// ---------------------------------------------------------------------------
// One-time: transpose state_below [T][B][I] -> sbT [T][I][B]
// ---------------------------------------------------------------------------
__global__ __launch_bounds__(256) void k_transpose_sb(const float* __restrict__ sb,
                                                      float* __restrict__ sbT) {
    __shared__ float tile[64][65];
    int bid = blockIdx.x;
    int t  = bid >> 3;          // 8 chunks of 64 i's per t
    int i0 = (bid & 7) << 6;
    const float* src = sb + (size_t)t * BATCH * IDIM;
    int tid = threadIdx.x;
    int row = tid >> 4;         // 0..15
    int c4  = (tid & 15) << 2;  // 0..60
#pragma unroll
    for (int rep = 0; rep < 4; ++rep) {
        int b = row + rep * 16;
        float4 v = *reinterpret_cast<const float4*>(src + (size_t)b * IDIM + i0 + c4);
        tile[b][c4 + 0] = v.x; tile[b][c4 + 1] = v.y;
        tile[b][c4 + 2] = v.z; tile[b][c4 + 3] = v.w;
    }
    __syncthreads();
    float* dst = sbT + ((size_t)t * IDIM + i0) * BATCH;
#pragma unroll
    for (int rep = 0; rep < 4; ++rep) {
        int ii = row + rep * 16;
        float4 v;
        v.x = tile[c4 + 0][ii]; v.y = tile[c4 + 1][ii];
        v.z = tile[c4 + 2][ii]; v.w = tile[c4 + 3][ii];
        *reinterpret_cast<float4*>(dst + (size_t)ii * BATCH + c4) = v;
    }
}

// ---------------------------------------------------------------------------
// One-time: build Wk[1536][3072], col c = (d>>2)*12 + (d&3)*3 + g
//   g=0: r-gate col d   (U / W)
//   g=1: u-gate col D+d (U / W)
//   g=2: cand col d     (Ux / Wx)
//   rows k<1024 from U/Ux; k>=1024 from W/Wx (row k-1024)
// ---------------------------------------------------------------------------
__global__ __launch_bounds__(256) void k_build_wk(const float* __restrict__ U,
                                                  const float* __restrict__ Ux,
                                                  const float* __restrict__ W,
                                                  const float* __restrict__ Wx,
                                                  float* __restrict__ Wk) {
    int k = blockIdx.x;
    int tid = threadIdx.x;
    float* orow = Wk + (size_t)k * NCOLS;
    for (int d = tid; d < DDIM; d += 256) {
        float vr, vu, vx;
        if (k < DDIM) {
            vr = U[(size_t)k * (2 * DDIM) + d];
            vu = U[(size_t)k * (2 * DDIM) + DDIM + d];
            vx = Ux[(size_t)k * DDIM + d];
        } else {
            int kp = k - DDIM;
            vr = W[(size_t)kp * (2 * DDIM) + d];
            vu = W[(size_t)kp * (2 * DDIM) + DDIM + d];
            vx = Wx[(size_t)kp * DDIM + d];
        }
        float* o = orow + (d >> 2) * 12 + (d & 3) * 3;
        o[0] = vr; o[1] = vu; o[2] = vx;
    }
}

// ---------------------------------------------------------------------------
// Per-timestep kernel. 256 blocks x 1024 threads (16 waves, 4/SIMD).
// Block dt owns d = dt*4 .. dt*4+3. Wave wid owns k in [wid*96, wid*96+96),
// computes partial sums for all 12 gate-cols (+4 separate x-part cand cols);
// lane = batch b. h/x read straight from global (each k by exactly one wave).
// Weights via wave-uniform scalar loads from Wk. One __syncthreads, then
// waves 0..3 reduce 16 partials and do the gate math.
// ---------------------------------------------------------------------------
__global__ __launch_bounds__(1024, 1) void k_step(const float* __restrict__ Wk,
                                                  const float* __restrict__ hp,  // [D][B]
                                                  float* __restrict__ hn,        // [D][B]
                                                  const float* __restrict__ xp,  // [I][B]
                                                  float* __restrict__ out_t,     // [B][D]
                                                  const float* __restrict__ bW,
                                                  const float* __restrict__ bWx,
                                                  const float* __restrict__ mask_t,
                                                  int first) {
    __shared__ float red[KSL][16][64];   // 64 KB: cols 0..11 = (dl,g); 12..15 = x-part cand

    int tid  = threadIdx.x;
    int lane = tid & 63;
    int wid  = tid >> 6;                 // 0..15
    int dt   = blockIdx.x;               // 0..255

    int k0 = __builtin_amdgcn_readfirstlane(wid * KPS);
    int k1 = k0 + KPS;

    float acc[12];
#pragma unroll
    for (int j = 0; j < 12; ++j) acc[j] = 0.f;
    float accX[4] = {0.f, 0.f, 0.f, 0.f};

    // ---- h part: k in [k0, min(k1,1024))
    int hEnd = k1 < DDIM ? k1 : DDIM;
    if (!first) {
#pragma unroll 4
        for (int k = k0; k < hEnd; ++k) {
            float hv = hp[(size_t)k * 64 + lane];
            const float* w = Wk + (size_t)k * NCOLS + dt * 12;
#pragma unroll
            for (int j = 0; j < 12; ++j) acc[j] += hv * w[j];
        }
    }

    // ---- x part: k in [max(k0,1024), k1)
    int xStart = k0 > DDIM ? k0 : DDIM;
#pragma unroll 4
    for (int k = xStart; k < k1; ++k) {
        float xv = xp[(size_t)(k - DDIM) * 64 + lane];
        const float* w = Wk + (size_t)k * NCOLS + dt * 12;
#pragma unroll
        for (int dl = 0; dl < 4; ++dl) {
            acc[dl * 3 + 0] += xv * w[dl * 3 + 0];
            acc[dl * 3 + 1] += xv * w[dl * 3 + 1];
            accX[dl]        += xv * w[dl * 3 + 2];
        }
    }

#pragma unroll
    for (int j = 0; j < 12; ++j) red[wid][j][lane] = acc[j];
#pragma unroll
    for (int dl = 0; dl < 4; ++dl) red[wid][12 + dl][lane] = accX[dl];
    __syncthreads();

    if (wid < 4) {
        int dl = wid;
        float sR = 0.f, sU = 0.f, sH = 0.f, sX = 0.f;
#pragma unroll
        for (int w = 0; w < KSL; ++w) {
            sR += red[w][dl * 3 + 0][lane];
            sU += red[w][dl * 3 + 1][lane];
            sH += red[w][dl * 3 + 2][lane];   // h @ Ux part
            sX += red[w][12 + dl][lane];      // x @ Wx part
        }
        int d = dt * 4 + dl;
        float hOld = 0.f;
        if (!first) hOld = hp[(size_t)d * 64 + lane];
        float m = mask_t[lane];

        float r  = 1.f / (1.f + expf(-(sR + bW[d])));
        float u  = 1.f / (1.f + expf(-(sU + bW[DDIM + d])));
        float hc = tanhf(sH * r + sX + bWx[d]);
        float hnew = u * hOld + (1.f - u) * hc;
        hnew = m * hnew + (1.f - m) * hOld;

        hn[(size_t)d * 64 + lane] = hnew;
        out_t[(size_t)lane * DDIM + d] = hnew;
    }
}

// ---------------------------------------------------------------------------
extern "C" void kernel_launch(void* const* d_in, const int* in_sizes, int n_in,
                              void* d_out, int out_size, void* d_ws, size_t ws_size,
                              hipStream_t stream) {
    const float* sb   = (const float*)d_in[0];
    const float* mask = (const float*)d_in[1];
    const float* W    = (const float*)d_in[2];
    const float* bW   = (const float*)d_in[3];
    const float* Wx   = (const float*)d_in[4];
    const float* bWx  = (const float*)d_in[5];
    const float* U    = (const float*)d_in[6];
    const float* Ux   = (const float*)d_in[7];
    float* out = (float*)d_out;
    float* ws  = (float*)d_ws;

    float* Wk  = ws;                                    // 1536*3072 f = 18.9 MB
    float* sbT = Wk + (size_t)KTOT * NCOLS;             // 512*512*64 f = 67.1 MB
    float* hT  = sbT + (size_t)T_STEPS * IDIM * BATCH;  // 2*1024*64 f  = 0.5 MB

    k_build_wk<<<dim3(KTOT), 256, 0, stream>>>(U, Ux, W, Wx, Wk);
    k_transpose_sb<<<dim3(T_STEPS * (IDIM / 64)), 256, 0, stream>>>(sb, sbT);

    for (int t = 0; t < T_STEPS; ++t) {
        float* hprev = hT + (size_t)(t & 1) * DDIM * BATCH;
        float* hnext = hT + (size_t)((t + 1) & 1) * DDIM * BATCH;
        k_step<<<dim3(DDIM / 4), 1024, 0, stream>>>(
            Wk, hprev, hnext,
            sbT + (size_t)t * IDIM * BATCH,
            out + (size_t)t * BATCH * DDIM,
            bW, bWx,
            mask + (size_t)t * BATCH,
            t == 0 ? 1 : 0);
    }
}

// Round 4
// 20000.354 us; speedup vs baseline: 4.5370x; 1.0024x over previous
//
#include <hip/hip_runtime.h>
#include <math.h>

#define T_STEPS 512
#define BATCH   64
#define IDIM    512
#define DDIM    1024
#define KTOT    1536
#define NCOLS   3072          // [dt 0..255][dl 0..3][g 0..2]
#define KSL     16            // k-slices = waves per block
#define KPS     96            // k per slice

// ---------------------------------------------------------------------------
// One-time: transpose state_below [T][B][I] -> sbT [T][I][B]
// ---------------------------------------------------------------------------
__global__ __launch_bounds__(256) void k_transpose_sb(const float* __restrict__ sb,
                                                      float* __restrict__ sbT) {
    __shared__ float tile[64][65];
    int bid = blockIdx.x;
    int t  = bid >> 3;          // 8 chunks of 64 i's per t
    int i0 = (bid & 7) << 6;
    const float* src = sb + (size_t)t * BATCH * IDIM;
    int tid = threadIdx.x;
    int row = tid >> 4;         // 0..15
    int c4  = (tid & 15) << 2;  // 0..60
#pragma unroll
    for (int rep = 0; rep < 4; ++rep) {
        int b = row + rep * 16;
        float4 v = *reinterpret_cast<const float4*>(src + (size_t)b * IDIM + i0 + c4);
        tile[b][c4 + 0] = v.x; tile[b][c4 + 1] = v.y;
        tile[b][c4 + 2] = v.z; tile[b][c4 + 3] = v.w;
    }
    __syncthreads();
    float* dst = sbT + ((size_t)t * IDIM + i0) * BATCH;
#pragma unroll
    for (int rep = 0; rep < 4; ++rep) {
        int ii = row + rep * 16;
        float4 v;
        v.x = tile[c4 + 0][ii]; v.y = tile[c4 + 1][ii];
        v.z = tile[c4 + 2][ii]; v.w = tile[c4 + 3][ii];
        *reinterpret_cast<float4*>(dst + (size_t)ii * BATCH + c4) = v;
    }
}

// ---------------------------------------------------------------------------
// One-time: build Wk[1536][3072], col c = (d>>2)*12 + (d&3)*3 + g
// ---------------------------------------------------------------------------
__global__ __launch_bounds__(256) void k_build_wk(const float* __restrict__ U,
                                                  const float* __restrict__ Ux,
                                                  const float* __restrict__ W,
                                                  const float* __restrict__ Wx,
                                                  float* __restrict__ Wk) {
    int k = blockIdx.x;
    int tid = threadIdx.x;
    float* orow = Wk + (size_t)k * NCOLS;
    for (int d = tid; d < DDIM; d += 256) {
        float vr, vu, vx;
        if (k < DDIM) {
            vr = U[(size_t)k * (2 * DDIM) + d];
            vu = U[(size_t)k * (2 * DDIM) + DDIM + d];
            vx = Ux[(size_t)k * DDIM + d];
        } else {
            int kp = k - DDIM;
            vr = W[(size_t)kp * (2 * DDIM) + d];
            vu = W[(size_t)kp * (2 * DDIM) + DDIM + d];
            vx = Wx[(size_t)kp * DDIM + d];
        }
        float* o = orow + (d >> 2) * 12 + (d & 3) * 3;
        o[0] = vr; o[1] = vu; o[2] = vx;
    }
}

// ---------------------------------------------------------------------------
// Per-timestep kernel. 256 blocks x 1024 threads (16 waves).
// Block dt owns d = dt*4 .. dt*4+3. Wave wid owns k in [wid*96, wid*96+96).
// lane = batch b. Writes ONLY hn[d*64+lane] ([D][B], coalesced, block-
// exclusive lines). Optional direct scattered out write for small-ws fallback.
// ---------------------------------------------------------------------------
__global__ __launch_bounds__(1024, 1) void k_step(const float* __restrict__ Wk,
                                                  const float* __restrict__ hp,  // [D][B]
                                                  float* __restrict__ hn,        // [D][B]
                                                  const float* __restrict__ xp,  // [I][B]
                                                  float* __restrict__ out_direct,// [B][D] or null
                                                  const float* __restrict__ bW,
                                                  const float* __restrict__ bWx,
                                                  const float* __restrict__ mask_t,
                                                  int first) {
    __shared__ float red[KSL][16][64];   // 64 KB

    int tid  = threadIdx.x;
    int lane = tid & 63;
    int wid  = tid >> 6;                 // 0..15
    int dt   = blockIdx.x;               // 0..255

    int k0 = __builtin_amdgcn_readfirstlane(wid * KPS);
    int k1 = k0 + KPS;

    float acc[12];
#pragma unroll
    for (int j = 0; j < 12; ++j) acc[j] = 0.f;
    float accX[4] = {0.f, 0.f, 0.f, 0.f};

    // ---- h part: k in [k0, min(k1,1024))
    int hEnd = k1 < DDIM ? k1 : DDIM;
    if (!first) {
#pragma unroll 4
        for (int k = k0; k < hEnd; ++k) {
            float hv = hp[(size_t)k * 64 + lane];
            const float* w = Wk + (size_t)k * NCOLS + dt * 12;
#pragma unroll
            for (int j = 0; j < 12; ++j) acc[j] += hv * w[j];
        }
    }

    // ---- x part: k in [max(k0,1024), k1)
    int xStart = k0 > DDIM ? k0 : DDIM;
#pragma unroll 4
    for (int k = xStart; k < k1; ++k) {
        float xv = xp[(size_t)(k - DDIM) * 64 + lane];
        const float* w = Wk + (size_t)k * NCOLS + dt * 12;
#pragma unroll
        for (int dl = 0; dl < 4; ++dl) {
            acc[dl * 3 + 0] += xv * w[dl * 3 + 0];
            acc[dl * 3 + 1] += xv * w[dl * 3 + 1];
            accX[dl]        += xv * w[dl * 3 + 2];
        }
    }

#pragma unroll
    for (int j = 0; j < 12; ++j) red[wid][j][lane] = acc[j];
#pragma unroll
    for (int dl = 0; dl < 4; ++dl) red[wid][12 + dl][lane] = accX[dl];
    __syncthreads();

    if (wid < 4) {
        int dl = wid;
        float sR = 0.f, sU = 0.f, sH = 0.f, sX = 0.f;
#pragma unroll
        for (int w = 0; w < KSL; ++w) {
            sR += red[w][dl * 3 + 0][lane];
            sU += red[w][dl * 3 + 1][lane];
            sH += red[w][dl * 3 + 2][lane];   // h @ Ux part
            sX += red[w][12 + dl][lane];      // x @ Wx part
        }
        int d = dt * 4 + dl;
        float hOld = 0.f;
        if (!first) hOld = hp[(size_t)d * 64 + lane];
        float m = mask_t[lane];

        float r  = 1.f / (1.f + expf(-(sR + bW[d])));
        float u  = 1.f / (1.f + expf(-(sU + bW[DDIM + d])));
        float hc = tanhf(sH * r + sX + bWx[d]);
        float hnew = u * hOld + (1.f - u) * hc;
        hnew = m * hnew + (1.f - m) * hOld;

        hn[(size_t)d * 64 + lane] = hnew;
        if (out_direct) out_direct[(size_t)lane * DDIM + d] = hnew;
    }
}

// ---------------------------------------------------------------------------
// Final: transpose hAll [T][D][B] -> out [T][B][D]. Grid = T*16 blocks,
// each handles one (t, 64-d chunk): reads 64x64 tile coalesced, writes
// out[t][b][d0..d0+63] (256 B per b, block-exclusive lines).
// ---------------------------------------------------------------------------
__global__ __launch_bounds__(256) void k_out_tr(const float* __restrict__ hAll,
                                                float* __restrict__ out) {
    __shared__ float tile[64][65];
    int bid = blockIdx.x;
    int t  = bid >> 4;
    int d0 = (bid & 15) << 6;
    const float* src = hAll + ((size_t)t * DDIM + d0) * BATCH;
    int tid = threadIdx.x;
    int row = tid >> 4;         // 0..15
    int c4  = (tid & 15) << 2;  // 0..60
#pragma unroll
    for (int rep = 0; rep < 4; ++rep) {
        int dd = row + rep * 16;
        float4 v = *reinterpret_cast<const float4*>(src + (size_t)dd * BATCH + c4);
        tile[dd][c4 + 0] = v.x; tile[dd][c4 + 1] = v.y;
        tile[dd][c4 + 2] = v.z; tile[dd][c4 + 3] = v.w;
    }
    __syncthreads();
    float* dst = out + (size_t)t * (BATCH * DDIM) + d0;
#pragma unroll
    for (int rep = 0; rep < 4; ++rep) {
        int b = row + rep * 16;
        float4 v;
        v.x = tile[c4 + 0][b]; v.y = tile[c4 + 1][b];
        v.z = tile[c4 + 2][b]; v.w = tile[c4 + 3][b];
        *reinterpret_cast<float4*>(dst + (size_t)b * DDIM + c4) = v;
    }
}

// ---------------------------------------------------------------------------
extern "C" void kernel_launch(void* const* d_in, const int* in_sizes, int n_in,
                              void* d_out, int out_size, void* d_ws, size_t ws_size,
                              hipStream_t stream) {
    const float* sb   = (const float*)d_in[0];
    const float* mask = (const float*)d_in[1];
    const float* W    = (const float*)d_in[2];
    const float* bW   = (const float*)d_in[3];
    const float* Wx   = (const float*)d_in[4];
    const float* bWx  = (const float*)d_in[5];
    const float* U    = (const float*)d_in[6];
    const float* Ux   = (const float*)d_in[7];
    float* out = (float*)d_out;
    float* ws  = (float*)d_ws;

    float* Wk  = ws;                                    // 1536*3072 f   = 18.9 MB
    float* sbT = Wk + (size_t)KTOT * NCOLS;             // 512*512*64 f  = 67.1 MB
    float* tail = sbT + (size_t)T_STEPS * IDIM * BATCH;

    size_t base_bytes = (size_t)(tail - ws) * 4;
    size_t hall_bytes = (size_t)T_STEPS * DDIM * BATCH * 4;   // 134.2 MB
    bool big_ws = ws_size >= base_bytes + hall_bytes;

    k_build_wk<<<dim3(KTOT), 256, 0, stream>>>(U, Ux, W, Wx, Wk);
    k_transpose_sb<<<dim3(T_STEPS * (IDIM / 64)), 256, 0, stream>>>(sb, sbT);

    if (big_ws) {
        // hAll[T][D][B]; step t reads hAll[t-1], writes hAll[t]; transpose at end.
        float* hAll = tail;
        for (int t = 0; t < T_STEPS; ++t) {
            const float* hprev = hAll + (size_t)(t - 1) * DDIM * BATCH;  // unused at t=0
            float* hnext = hAll + (size_t)t * DDIM * BATCH;
            k_step<<<dim3(DDIM / 4), 1024, 0, stream>>>(
                Wk, t == 0 ? hAll : hprev, hnext,
                sbT + (size_t)t * IDIM * BATCH,
                nullptr,
                bW, bWx,
                mask + (size_t)t * BATCH,
                t == 0 ? 1 : 0);
        }
        k_out_tr<<<dim3(T_STEPS * 16), 256, 0, stream>>>(hAll, out);
    } else {
        // Fallback (round-3 behavior): ping-pong h + direct scattered out write.
        float* hT = tail;                                // 2*1024*64 f = 0.5 MB
        for (int t = 0; t < T_STEPS; ++t) {
            float* hprev = hT + (size_t)(t & 1) * DDIM * BATCH;
            float* hnext = hT + (size_t)((t + 1) & 1) * DDIM * BATCH;
            k_step<<<dim3(DDIM / 4), 1024, 0, stream>>>(
                Wk, hprev, hnext,
                sbT + (size_t)t * IDIM * BATCH,
                out + (size_t)t * BATCH * DDIM,
                bW, bWx,
                mask + (size_t)t * BATCH,
                t == 0 ? 1 : 0);
        }
    }
}

// Round 5
// 8225.619 us; speedup vs baseline: 11.0315x; 2.4315x over previous
//
#include <hip/hip_runtime.h>
#include <math.h>

#define T_STEPS 512
#define BATCH   64
#define IDIM    512
#define DDIM    1024
#define KH      1024
#define KX      512
#define KT      1536

typedef unsigned short ushort_t;
typedef __attribute__((ext_vector_type(8))) short short8;
typedef __attribute__((ext_vector_type(4))) short short4v;
typedef __attribute__((ext_vector_type(4))) float f32x4;

__device__ __forceinline__ ushort_t f2bf(float f) {
    unsigned int u = __float_as_uint(f);
    u += 0x7fff + ((u >> 16) & 1);          // RNE
    return (ushort_t)(u >> 16);
}
__device__ __forceinline__ float bf2f(ushort_t s) {
    return __uint_as_float(((unsigned int)s) << 16);
}

// ---------------------------------------------------------------------------
// One-time: weights -> Ab[dc 0..63][g 0..2][s 0..1][m 0..15][k 0..1535] bf16
//   g=0: r-gate col d (U rows k<1024, W rows k>=1024)
//   g=1: u-gate col D+d
//   g=2: cand col d (Ux / Wx)
//   s=0: bf16(w), s=1: bf16(w - bf16(w))   (double-bf16 split)
// ---------------------------------------------------------------------------
__global__ __launch_bounds__(256) void k_build_A(const float* __restrict__ U,
                                                 const float* __restrict__ Ux,
                                                 const float* __restrict__ W,
                                                 const float* __restrict__ Wx,
                                                 ushort_t* __restrict__ Ab) {
    int blk = blockIdx.x;            // 0..191 = dc*3+g
    int dc = blk / 3, g = blk % 3;
    int tid = threadIdx.x;
    int m = tid & 15, kb = tid >> 4;
    int col = dc * 16 + m;
    size_t rowbase = ((((size_t)dc * 3 + g) * 2 + 0) * 16 + m) * KT;
    for (int k = kb; k < KT; k += 16) {
        float w;
        if (g == 2) {
            w = (k < KH) ? Ux[(size_t)k * DDIM + col]
                         : Wx[(size_t)(k - KH) * DDIM + col];
        } else {
            int c2 = col + (g == 1 ? DDIM : 0);
            w = (k < KH) ? U[(size_t)k * (2 * DDIM) + c2]
                         : W[(size_t)(k - KH) * (2 * DDIM) + c2];
        }
        ushort_t w1 = f2bf(w);
        ushort_t w2 = f2bf(w - bf2f(w1));
        Ab[rowbase + k] = w1;
        Ab[rowbase + (size_t)16 * KT + k] = w2;   // s=1
    }
}

// ---------------------------------------------------------------------------
// One-time: state_below -> sbB[t][s][bt][r 0..15][i 0..511] bf16 (split pair)
// ---------------------------------------------------------------------------
__global__ __launch_bounds__(256) void k_build_sbB(const float* __restrict__ sb,
                                                   ushort_t* __restrict__ sbB) {
    int blk = blockIdx.x;            // 0..2047 = t*4+bt
    int t = blk >> 2, bt = blk & 3;
    int tid = threadIdx.x;
    int r = tid >> 4, c = tid & 15;
    const float* src = sb + ((size_t)t * BATCH + bt * 16 + r) * IDIM;
    ushort_t* d1 = sbB + ((((size_t)t * 2 + 0) * 4 + bt) * 16 + r) * KX;
    ushort_t* d2 = sbB + ((((size_t)t * 2 + 1) * 4 + bt) * 16 + r) * KX;
#pragma unroll
    for (int rep = 0; rep < 8; ++rep) {
        int i = c * 4 + rep * 64;
        float4 v = *(const float4*)(src + i);
        ushort_t a0 = f2bf(v.x), a1 = f2bf(v.y), a2 = f2bf(v.z), a3 = f2bf(v.w);
        short4v p1 = {(short)a0, (short)a1, (short)a2, (short)a3};
        *(short4v*)(d1 + i) = p1;
        ushort_t b0 = f2bf(v.x - bf2f(a0)), b1 = f2bf(v.y - bf2f(a1));
        ushort_t b2 = f2bf(v.z - bf2f(a2)), b3 = f2bf(v.w - bf2f(a3));
        short4v p2 = {(short)b0, (short)b1, (short)b2, (short)b3};
        *(short4v*)(d2 + i) = p2;
    }
}

// ---------------------------------------------------------------------------
// Per-step MFMA kernel. Grid 256 = (dc 0..63) x (bt 0..3), XCD-swizzled.
// 768 threads = 12 waves = (g 0..2) x (kq 0..3).
//   kq 0,1: h-part K [0,512),[512,1024) -> B frags from LDS (staged, swizzled)
//   kq 2,3: x-part K [1024,1280),[1280,1536) -> B frags direct from sbB
// 3-product double-bf16: acc += A2*B1 + A1*B2 + A1*B1 (fp32 accumulate).
// Epilogue (wave 0): reduce 12 partials, gates, mask, write fp32 out[t]
// (coalesced, block-exclusive 64B lines) + split-bf16 h for next step.
// ---------------------------------------------------------------------------
__global__ __launch_bounds__(768, 1) void k_step(
    const ushort_t* __restrict__ Ab, const ushort_t* __restrict__ sbB_t,
    const ushort_t* __restrict__ hBin, ushort_t* __restrict__ hBout,
    float* __restrict__ out_t, const float* __restrict__ out_prev,
    const float* __restrict__ bW, const float* __restrict__ bWx,
    const float* __restrict__ mask_t, int first)
{
    __shared__ __align__(16) char lds[65536];   // [s][16 rows][2048 B] swizzled

    int tid = threadIdx.x;
    int lane = tid & 63;
    int wid = tid >> 6;                  // 0..11
    int bid = blockIdx.x;
    int dc = (bid & 7) * 8 + ((bid >> 3) & 7);  // same-dc blocks -> same XCD
    int bt = bid >> 6;

    // ---- stage h-part B1/B2 into LDS (XOR-swizzled rows)
    if (!first) {
        for (int j = tid; j < 4096; j += 768) {
            int s = j >> 11, jj = j & 2047;
            int r = jj >> 7, c16 = jj & 127;
            const ushort_t* src = hBin + (((size_t)s * 4 + bt) * 16 + r) * KH + c16 * 8;
            short8 v = *(const short8*)src;
            int dst = s * 32768 + r * 2048 + ((c16 << 4) ^ ((r & 7) << 4));
            *(short8*)(lds + dst) = v;
        }
    }
    __syncthreads();

    int g = wid >> 2, kq = wid & 3;
    int m = lane & 15, q = lane >> 4;

    f32x4 acc = {0.f, 0.f, 0.f, 0.f};
    const ushort_t* a1p = Ab + ((((size_t)dc * 3 + g) * 2 + 0) * 16 + m) * KT;
    const ushort_t* a2p = a1p + (size_t)16 * KT;

    if (kq < 2) {
        if (!first) {
            int ks0 = kq * 16, ks1 = ks0 + 16;
            for (int ks = ks0; ks < ks1; ++ks) {
                int ke = ks * 32 + q * 8;
                short8 A1 = *(const short8*)(a1p + ke);
                short8 A2 = *(const short8*)(a2p + ke);
                int boff = m * 2048 + ((ks * 64 + q * 16) ^ ((m & 7) << 4));
                short8 B1 = *(const short8*)(lds + boff);
                short8 B2 = *(const short8*)(lds + 32768 + boff);
                acc = __builtin_amdgcn_mfma_f32_16x16x32_bf16(A2, B1, acc, 0, 0, 0);
                acc = __builtin_amdgcn_mfma_f32_16x16x32_bf16(A1, B2, acc, 0, 0, 0);
                acc = __builtin_amdgcn_mfma_f32_16x16x32_bf16(A1, B1, acc, 0, 0, 0);
            }
        }
    } else {
        int ks0 = (kq - 2) * 8, ks1 = ks0 + 8;
        const ushort_t* x1p = sbB_t + ((size_t)bt * 16 + m) * KX;
        const ushort_t* x2p = x1p + (size_t)4 * 16 * KX;   // s=1 slice
        for (int ks = ks0; ks < ks1; ++ks) {
            int ke = KH + ks * 32 + q * 8;
            int kx = ks * 32 + q * 8;
            short8 A1 = *(const short8*)(a1p + ke);
            short8 A2 = *(const short8*)(a2p + ke);
            short8 B1 = *(const short8*)(x1p + kx);
            short8 B2 = *(const short8*)(x2p + kx);
            acc = __builtin_amdgcn_mfma_f32_16x16x32_bf16(A2, B1, acc, 0, 0, 0);
            acc = __builtin_amdgcn_mfma_f32_16x16x32_bf16(A1, B2, acc, 0, 0, 0);
            acc = __builtin_amdgcn_mfma_f32_16x16x32_bf16(A1, B1, acc, 0, 0, 0);
        }
    }

    // ---- reduce partials (overlay red[12][4][64] f32 on the LDS buffer)
    __syncthreads();
    float* redf = (float*)lds;
    redf[wid * 256 + 0 * 64 + lane] = acc.x;
    redf[wid * 256 + 1 * 64 + lane] = acc.y;
    redf[wid * 256 + 2 * 64 + lane] = acc.z;
    redf[wid * 256 + 3 * 64 + lane] = acc.w;
    __syncthreads();

    if (tid < 64) {
        int n = tid & 15, qq = tid >> 4;
        int b = bt * 16 + n;
        int dbase = dc * 16 + qq * 4;
        float4 bWr = *(const float4*)(bW + dbase);
        float4 bWu = *(const float4*)(bW + DDIM + dbase);
        float4 bXx = *(const float4*)(bWx + dbase);
        float mk = mask_t[b];
        float4 hold = {0.f, 0.f, 0.f, 0.f};
        if (!first) hold = *(const float4*)(out_prev + (size_t)b * DDIM + dbase);

        float res[4];
        ushort_t h1[4], h2[4];
#pragma unroll
        for (int rg = 0; rg < 4; ++rg) {
            float sR = 0.f, sU = 0.f;
#pragma unroll
            for (int w2 = 0; w2 < 4; ++w2) sR += redf[w2 * 256 + rg * 64 + tid];
#pragma unroll
            for (int w2 = 4; w2 < 8; ++w2) sU += redf[w2 * 256 + rg * 64 + tid];
            float sH = redf[8 * 256 + rg * 64 + tid] + redf[9 * 256 + rg * 64 + tid];
            float sX = redf[10 * 256 + rg * 64 + tid] + redf[11 * 256 + rg * 64 + tid];
            float ho = (rg == 0) ? hold.x : (rg == 1) ? hold.y : (rg == 2) ? hold.z : hold.w;
            float bR = (rg == 0) ? bWr.x : (rg == 1) ? bWr.y : (rg == 2) ? bWr.z : bWr.w;
            float bU = (rg == 0) ? bWu.x : (rg == 1) ? bWu.y : (rg == 2) ? bWu.z : bWu.w;
            float bX = (rg == 0) ? bXx.x : (rg == 1) ? bXx.y : (rg == 2) ? bXx.z : bXx.w;
            float r = 1.f / (1.f + __expf(-(sR + bR)));
            float u = 1.f / (1.f + __expf(-(sU + bU)));
            float hc = tanhf(sH * r + sX + bX);
            float hnv = u * ho + (1.f - u) * hc;
            hnv = mk * hnv + (1.f - mk) * ho;
            res[rg] = hnv;
            h1[rg] = f2bf(hnv);
            h2[rg] = f2bf(hnv - bf2f(h1[rg]));
        }
        float4 o = {res[0], res[1], res[2], res[3]};
        *(float4*)(out_t + (size_t)b * DDIM + dbase) = o;
        short4v p1 = {(short)h1[0], (short)h1[1], (short)h1[2], (short)h1[3]};
        short4v p2 = {(short)h2[0], (short)h2[1], (short)h2[2], (short)h2[3]};
        *(short4v*)(hBout + ((size_t)bt * 16 + n) * KH + dbase) = p1;
        *(short4v*)(hBout + (size_t)4 * 16 * KH + ((size_t)bt * 16 + n) * KH + dbase) = p2;
    }
}

// ---------------------------------------------------------------------------
extern "C" void kernel_launch(void* const* d_in, const int* in_sizes, int n_in,
                              void* d_out, int out_size, void* d_ws, size_t ws_size,
                              hipStream_t stream) {
    const float* sb   = (const float*)d_in[0];
    const float* mask = (const float*)d_in[1];
    const float* W    = (const float*)d_in[2];
    const float* bW   = (const float*)d_in[3];
    const float* Wx   = (const float*)d_in[4];
    const float* bWx  = (const float*)d_in[5];
    const float* U    = (const float*)d_in[6];
    const float* Ux   = (const float*)d_in[7];
    float* out = (float*)d_out;

    // ws layout (bf16 elems): Ab 9,437,184 | sbB 33,554,432 | hB 2x131,072
    // total 86.5 MB (same budget as the round-1 kernel that passed)
    ushort_t* Ab  = (ushort_t*)d_ws;
    ushort_t* sbB = Ab + (size_t)2 * 3072 * KT;             // 9,437,184
    ushort_t* hB  = sbB + (size_t)T_STEPS * 2 * 4 * 16 * KX; // +33,554,432

    k_build_A<<<dim3(192), 256, 0, stream>>>(U, Ux, W, Wx, Ab);
    k_build_sbB<<<dim3(T_STEPS * 4), 256, 0, stream>>>(sb, sbB);

    const size_t hP = (size_t)2 * 4 * 16 * KH;   // 131072 elems per ping buffer
    for (int t = 0; t < T_STEPS; ++t) {
        k_step<<<dim3(256), 768, 0, stream>>>(
            Ab,
            sbB + (size_t)t * 2 * 4 * 16 * KX,
            hB + (size_t)(t & 1) * hP,
            hB + (size_t)((t + 1) & 1) * hP,
            out + (size_t)t * BATCH * DDIM,
            t ? out + (size_t)(t - 1) * BATCH * DDIM : out,
            bW, bWx,
            mask + (size_t)t * BATCH,
            t == 0 ? 1 : 0);
    }
}